// Round 2
// baseline (90.332 us; speedup 1.0000x reference)
//
#include <hip/hip_runtime.h>

// GlobalAttentionModule collapses algebraically:
//   weight = softmax(score, axis=-1)  =>  sum_j weight[b,c,i,j] == 1
//   out = (v[:,:,:,None] * weight).sum(-1) = v
// where v = relu(GroupNorm32(Wv @ feat + bv, gn_v_g, gn_v_b)).
// Only inputs 0 (feat), 5 (Wv), 6 (bv), 7 (gn_v_g), 8 (gn_v_b) matter.
//
// Perf note: the timed window contains two harness-side 268 MB poison fills
// (~80.5 us at 83% HBM peak) — a fixed floor. The controllable slice is the
// rest. This version: ONE kernel, 64 blocks x 1024 threads. Split-K inside
// the block: thread (s,p) accumulates 32 of the 128 input channels (32
// independent float2 loads, fully unrolled), partials meet in LDS, then the
// GroupNorm reduction + normalize happen in the same block. 16 waves/CU
// (4/SIMD) hides load latency; no workspace, no second launch.

#define BATCH   2
#define CH      128
#define NPOS    512
#define GROUPS  32
#define CPG     4               // channels per group = 128/32
#define KSLICES 4               // split-K factor inside the block
#define KC      (CH / KSLICES)  // 32 input channels per slice
#define PPT     (NPOS / 2)      // 256 position pairs per block
#define GEPS    1e-5f

__global__ __launch_bounds__(1024) void vpath_fused(
    const float* __restrict__ feat,   // [B, C, N]
    const float* __restrict__ Wv,     // [C, C]  (out_ch, in_ch)
    const float* __restrict__ bv,     // [C]
    const float* __restrict__ gam,    // [C]
    const float* __restrict__ bet,    // [C]
    float* __restrict__ out)          // [B, C, N]
{
    const int b   = blockIdx.x >> 5;
    const int g   = blockIdx.x & 31;
    const int ch0 = g * CPG;
    const int t   = threadIdx.x;      // 0..1023
    const int s   = t >> 8;           // k-slice 0..3 (uniform per wave)
    const int p   = t & 255;          // position pair: positions 2p, 2p+1

    __shared__ float  w[CPG][CH];             // 2 KB: Wv rows of this group
    __shared__ float2 part[KSLICES][CPG][PPT]; // 32 KB: split-K partials
    __shared__ float  red[32];
    __shared__ float  stats[2];

    // Stage the 4 Wv rows (512 floats; threads 0..511 load one each).
    if (t < CPG * CH) {
        int j = t >> 7, c = t & (CH - 1);
        w[j][c] = Wv[(ch0 + j) * CH + c];
    }
    __syncthreads();

    // Phase 1: partial dot over c in [32s, 32s+32) for all 4 channels.
    // 32 independent coalesced float2 loads per thread, fully unrolled.
    float a0[CPG] = {0.f, 0.f, 0.f, 0.f};
    float a1[CPG] = {0.f, 0.f, 0.f, 0.f};
    const float2* fp = reinterpret_cast<const float2*>(
        feat + (size_t)b * CH * NPOS) + p;
    #pragma unroll
    for (int cc = 0; cc < KC; ++cc) {
        const int c = s * KC + cc;
        float2 f = fp[c * (NPOS / 2)];
        #pragma unroll
        for (int j = 0; j < CPG; ++j) {
            float wv = w[j][c];               // LDS broadcast (wave-uniform)
            a0[j] = fmaf(wv, f.x, a0[j]);
            a1[j] = fmaf(wv, f.y, a1[j]);
        }
    }
    #pragma unroll
    for (int j = 0; j < CPG; ++j)
        part[s][j][p] = make_float2(a0[j], a1[j]);
    __syncthreads();

    // Phase 2: thread (s,p) owns channel ch0+s, positions 2p,2p+1.
    const int j2 = s;
    float v0 = bv[ch0 + j2], v1 = v0;
    #pragma unroll
    for (int s2 = 0; s2 < KSLICES; ++s2) {
        float2 q = part[s2][j2][p];
        v0 += q.x;
        v1 += q.y;
    }

    // GroupNorm stats over the 2048 group values (each counted once).
    float su = v0 + v1;
    float sq = v0 * v0 + v1 * v1;
    #pragma unroll
    for (int off = 32; off > 0; off >>= 1) {
        su += __shfl_down(su, off);
        sq += __shfl_down(sq, off);
    }
    const int wave = t >> 6;
    if ((t & 63) == 0) { red[wave] = su; red[wave + 16] = sq; }
    __syncthreads();
    if (t == 0) {
        float S = 0.f, S2 = 0.f;
        #pragma unroll
        for (int i = 0; i < 16; ++i) { S += red[i]; S2 += red[i + 16]; }
        const float inv_n = 1.0f / (float)(CPG * NPOS);   // 1/2048
        float m = S * inv_n;
        stats[0] = m;
        stats[1] = rsqrtf(S2 * inv_n - m * m + GEPS);
    }
    __syncthreads();

    // Normalize + affine + ReLU, coalesced float2 store.
    const float m  = stats[0];
    const float r  = stats[1];
    const float ga = gam[ch0 + j2] * r;
    const float be = fmaf(-m, ga, bet[ch0 + j2]);   // y = v*ga + be
    float2 y;
    y.x = fmaxf(fmaf(v0, ga, be), 0.0f);
    y.y = fmaxf(fmaf(v1, ga, be), 0.0f);
    reinterpret_cast<float2*>(
        out + ((size_t)(b * CH + ch0 + j2)) * NPOS)[p] = y;
}

extern "C" void kernel_launch(void* const* d_in, const int* in_sizes, int n_in,
                              void* d_out, int out_size, void* d_ws, size_t ws_size,
                              hipStream_t stream) {
    const float* feat = (const float*)d_in[0];   // [2,128,512]
    const float* Wv   = (const float*)d_in[5];   // [128,128]
    const float* bv   = (const float*)d_in[6];   // [128]
    const float* gng  = (const float*)d_in[7];   // [128]
    const float* gnb  = (const float*)d_in[8];   // [128]
    float* out = (float*)d_out;                  // [2,128,512]

    vpath_fused<<<dim3(BATCH * GROUPS), dim3(1024), 0, stream>>>(
        feat, Wv, bv, gng, gnb, out);
}